// Round 3
// baseline (124.673 us; speedup 1.0000x reference)
//
#include <hip/hip_runtime.h>

// ActionVectorQuantizer: z [B=8, T=32768, D=256] f32, emb [8, 256] f32
// out0 = emb[argmin_c ||z - e_c||^2]  (STE forward value == z_q)
// out1 = argmin index, stored as float (harness reads whole d_out as f32)

#define NC   8
#define DIM  256
#define TPW  32            // tokens per wave
#define WPB  4             // waves per block
#define THREADS (WPB * 64)

// Fold 8 per-lane partial sums (a[0..7]) into one full sum per lane.
// After fold, lane l holds the total (over all 64 lanes) for code
//   c(l) = 4*(l&1) + 2*((l>>1)&1) + ((l>>2)&1)
// Tree: masks 1,2,4 halve the accumulator count (7 shuffles), then
// masks 8,16,32 sum across the eight 8-lane groups (3 shuffles).
__device__ __forceinline__ double fold8(const double (&a)[NC], int b0, int b1, int b2)
{
    double t[4];
#pragma unroll
    for (int i = 0; i < 4; ++i) {
        double lo = a[i], hi = a[i + 4];
        double keep = b0 ? hi : lo;          // static indices only (no scratch)
        double send = b0 ? lo : hi;
        t[i] = keep + __shfl_xor(send, 1, 64);
    }
    double u[2];
#pragma unroll
    for (int i = 0; i < 2; ++i) {
        double lo = t[i], hi = t[i + 2];
        double keep = b1 ? hi : lo;
        double send = b1 ? lo : hi;
        u[i] = keep + __shfl_xor(send, 2, 64);
    }
    double lo = u[0], hi = u[1];
    double keep = b2 ? hi : lo;
    double send = b2 ? lo : hi;
    double v = keep + __shfl_xor(send, 4, 64);
    v += __shfl_xor(v, 8, 64);
    v += __shfl_xor(v, 16, 64);
    v += __shfl_xor(v, 32, 64);
    return v;
}

__global__ __launch_bounds__(THREADS, 4)
void vq_kernel(const float* __restrict__ z, const float* __restrict__ emb,
               float* __restrict__ zq, float* __restrict__ fidx)
{
    __shared__ float semb[NC * DIM];   // 8 KiB: f32 emb copy for z_q gather
    for (int i = threadIdx.x; i < (NC * DIM) / 4; i += THREADS)
        reinterpret_cast<float4*>(semb)[i] = reinterpret_cast<const float4*>(emb)[i];
    __syncthreads();

    const int lane = threadIdx.x & 63;
    const int wid  = blockIdx.x * WPB + (threadIdx.x >> 6);
    const int b0 = lane & 1, b1 = (lane >> 1) & 1, b2 = (lane >> 2) & 1;
    const int cidx = 4 * b0 + 2 * b1 + b2;   // code this lane represents post-fold

    // Per-lane emb fragment in f64: e64[c][j] = emb[c][4*lane + j]
    double e64[NC][4];
#pragma unroll
    for (int c = 0; c < NC; ++c) {
        const float4 ev = *reinterpret_cast<const float4*>(&semb[c * DIM + 4 * lane]);
        e64[c][0] = (double)ev.x; e64[c][1] = (double)ev.y;
        e64[c][2] = (double)ev.z; e64[c][3] = (double)ev.w;
    }

    // ||e_c||^2 per lane-mapped code (f64, exact products)
    double es[NC];
#pragma unroll
    for (int c = 0; c < NC; ++c)
        es[c] = (e64[c][0] * e64[c][0] + e64[c][1] * e64[c][1])
              + (e64[c][2] * e64[c][2] + e64[c][3] * e64[c][3]);
    const double esq_my = fold8(es, b0, b1, b2);

    const long long tok0 = (long long)wid * TPW;
    const float* zp = z  + tok0 * DIM + 4 * lane;
    float*       qp = zq + tok0 * DIM + 4 * lane;

    float myidx = 0.0f;
    float4 zv = *reinterpret_cast<const float4*>(zp);   // prefetch token 0

    for (int t = 0; t < TPW; ++t) {
        // software-pipelined prefetch of next token's z row
        float4 zn = zv;
        if (t + 1 < TPW)
            zn = *reinterpret_cast<const float4*>(zp + (size_t)(t + 1) * DIM);

        const double z0 = (double)zv.x, z1 = (double)zv.y,
                     z2 = (double)zv.z, z3 = (double)zv.w;

        // 8 per-lane dot partials (f64: f32*f32 products exact)
        double acc[NC];
#pragma unroll
        for (int c = 0; c < NC; ++c)
            acc[c] = (z0 * e64[c][0] + z1 * e64[c][1])
                   + (z2 * e64[c][2] + z3 * e64[c][3]);

        const double dot = fold8(acc, b0, b1, b2);
        // argmin of ||z||^2 + ||e||^2 - 2 z.e  ==  argmin of ||e||^2 - 2 z.e
        double dist = esq_my - 2.0 * dot;
        int ci = cidx;

        // argmin butterfly within each 8-lane group (groups are identical),
        // lexicographic (dist, idx) min == numpy argmin first-occurrence
#pragma unroll
        for (int m = 1; m <= 4; m <<= 1) {
            double od = __shfl_xor(dist, m, 64);
            int    oc = __shfl_xor(ci,   m, 64);
            bool take = (od < dist) || ((od == dist) && (oc < ci));
            dist = take ? od : dist;
            ci   = take ? oc : ci;
        }
        // all 64 lanes now agree on ci

        const float4 q = *reinterpret_cast<const float4*>(&semb[ci * DIM + 4 * lane]);
        *reinterpret_cast<float4*>(qp + (size_t)t * DIM) = q;

        if (lane == t) myidx = (float)ci;   // lane t keeps token t's index
        zv = zn;
    }

    // coalesced idx store: lanes 0..31 write 32 consecutive floats
    if (lane < TPW) fidx[tok0 + lane] = myidx;
}

extern "C" void kernel_launch(void* const* d_in, const int* in_sizes, int n_in,
                              void* d_out, int out_size, void* d_ws, size_t ws_size,
                              hipStream_t stream)
{
    const float* z   = (const float*)d_in[0];
    const float* emb = (const float*)d_in[1];
    float* out = (float*)d_out;

    const long long ntok = (long long)in_sizes[0] / DIM;   // 262144
    float* zq   = out;
    float* fidx = out + (size_t)ntok * DIM;                 // idx region (as floats)

    const int waves  = (int)(ntok / TPW);    // 8192
    const int blocks = waves / WPB;          // 2048

    vq_kernel<<<blocks, THREADS, 0, stream>>>(z, emb, zq, fidx);
}

// Round 4
// 115.993 us; speedup vs baseline: 1.0748x; 1.0748x over previous
//
#include <hip/hip_runtime.h>

// ActionVectorQuantizer: z [8*32768, 256] f32, emb [8, 256] f32
// out0 = emb[argmin_c ||z-e_c||^2] (f32), out1 = idx stored as f32.
//
// Layout: lane = (c2=bit0, g=bits1..5). Lane owns dims 8g..8g+7 (chunks
// lane, lane^1) and codes {4*c2+m, m=0..3}. Per token: in-lane f64 dots,
// fold masks {2,4} -> 1 value/lane. Every 8 tokens: transpose-fold masks
// {8,16,32} (token tau = bits3..5), packed-key argmin masks {1,2,4}.
// All distances in f64 (exact f32 products) -> argmin matches the
// verified round-2 kernel bit-for-bit up to ~1e-16 reassociation.

#define NC   8
#define DIM  256
#define TPW  32            // tokens per wave
#define WPB  4             // waves per block
#define THREADS (WPB * 64)

__global__ __launch_bounds__(THREADS, 3)
void vq_kernel(const float* __restrict__ z, const float* __restrict__ emb,
               float* __restrict__ zq, float* __restrict__ fidx)
{
    const int lane = threadIdx.x & 63;
    const int wid  = blockIdx.x * WPB + (threadIdx.x >> 6);

    const int c2 = lane & 1;
    const int b1 = (lane >> 1) & 1, b2 = (lane >> 2) & 1;
    const int b3 = (lane >> 3) & 1, b4 = (lane >> 4) & 1, b5 = (lane >> 5) & 1;
    const int kappa = 4 * c2 + 2 * b1 + b2;     // code this lane owns post-fold
    const int grp   = lane >> 3;                 // 8-lane group (tail phase)
    const int gidx  = lane & 7;                  // lane within group
    const int tau   = 4 * b3 + 2 * b4 + b5;      // batch-local token post-transpose

    // emb fragments in f64: e64[m][0..3] <-> chunk `lane`, [4..7] <-> chunk `lane^1`
    // (chunk c = dims 4c..4c+3; lane's dims = chunks {lane, lane^1})
    double e64[4][8];
#pragma unroll
    for (int m = 0; m < 4; ++m) {
        const int row = 4 * c2 + m;
        const float4 ea = *reinterpret_cast<const float4*>(emb + row * DIM + 4 * lane);
        const float4 eb = *reinterpret_cast<const float4*>(emb + row * DIM + 4 * (lane ^ 1));
        e64[m][0] = ea.x; e64[m][1] = ea.y; e64[m][2] = ea.z; e64[m][3] = ea.w;
        e64[m][4] = eb.x; e64[m][5] = eb.y; e64[m][6] = eb.z; e64[m][7] = eb.w;
    }

    // ||e_kappa||^2 via the same fold pipeline (one-time)
    double es[4];
#pragma unroll
    for (int m = 0; m < 4; ++m) {
        double s = 0.0;
#pragma unroll
        for (int j = 0; j < 8; ++j) s += e64[m][j] * e64[m][j];
        es[m] = s;
    }
    double est[2];
#pragma unroll
    for (int i = 0; i < 2; ++i) {
        double keep = b1 ? es[i + 2] : es[i];
        double send = b1 ? es[i]     : es[i + 2];
        est[i] = keep + __shfl_xor(send, 2, 64);
    }
    double esv = (b2 ? est[1] : est[0]) + __shfl_xor(b2 ? est[0] : est[1], 4, 64);
    esv += __shfl_xor(esv, 8, 64);
    esv += __shfl_xor(esv, 16, 64);
    esv += __shfl_xor(esv, 32, 64);
    const double esq_my = esv;   // ||e_kappa||^2, exact f64

    const long long tok0 = (long long)wid * TPW;
    const float4* zf4 = reinterpret_cast<const float4*>(z + tok0 * DIM);

    // depth-2 prefetch pipeline (all names static; no runtime-indexed arrays)
    float4 cA  = zf4[lane],            cB  = zf4[lane ^ 1];            // token 0
    float4 p1A = zf4[64 + lane],       p1B = zf4[64 + (lane ^ 1)];     // token 1

    double val[8];

    for (int b = 0; b < 4; ++b) {
#pragma unroll
        for (int t = 0; t < 8; ++t) {
            const int bt  = b * 8 + t;
            const int nxt = (bt + 2 <= TPW - 1) ? (bt + 2) : (TPW - 1);
            float4 p2A = zf4[nxt * 64 + lane];
            float4 p2B = zf4[nxt * 64 + (lane ^ 1)];

            const double z0 = cA.x, z1 = cA.y, z2 = cA.z, z3 = cA.w;
            const double z4 = cB.x, z5 = cB.y, z6 = cB.z, z7 = cB.w;

            double acc[4];
#pragma unroll
            for (int m = 0; m < 4; ++m)
                acc[m] = ((z0 * e64[m][0] + z1 * e64[m][1]) + (z2 * e64[m][2] + z3 * e64[m][3]))
                       + ((z4 * e64[m][4] + z5 * e64[m][5]) + (z6 * e64[m][6] + z7 * e64[m][7]));

            // per-token fold: masks {2,4} -> 1 partial/lane (code kappa, 32 dims)
            double ft[2];
#pragma unroll
            for (int i = 0; i < 2; ++i) {
                double keep = b1 ? acc[i + 2] : acc[i];
                double send = b1 ? acc[i]     : acc[i + 2];
                ft[i] = keep + __shfl_xor(send, 2, 64);
            }
            val[t] = (b2 ? ft[1] : ft[0]) + __shfl_xor(b2 ? ft[0] : ft[1], 4, 64);

            cA = p1A; cB = p1B; p1A = p2A; p1B = p2B;
        }

        // ===== batched tail for tokens b*8 .. b*8+7 =====
        // transpose-fold masks {8,16,32}: lane ends with full dot for
        // (token tau, code kappa)
        double tt[4];
#pragma unroll
        for (int i = 0; i < 4; ++i) {
            double keep = b3 ? val[i + 4] : val[i];
            double send = b3 ? val[i]     : val[i + 4];
            tt[i] = keep + __shfl_xor(send, 8, 64);
        }
        double uu[2];
#pragma unroll
        for (int i = 0; i < 2; ++i) {
            double keep = b4 ? tt[i + 2] : tt[i];
            double send = b4 ? tt[i]     : tt[i + 2];
            uu[i] = keep + __shfl_xor(send, 16, 64);
        }
        const double dot = (b5 ? uu[1] : uu[0]) + __shfl_xor(b5 ? uu[0] : uu[1], 32, 64);

        // argmin of ||z||^2 + ||e||^2 - 2 z.e == argmin of ||e||^2 - 2 z.e
        const double dist = esq_my - 2.0 * dot;

        // order-preserving f64 -> u64 key, code idx in low 3 bits
        // (perturbation 2^-50 relative; equal dists -> lower code wins ==
        //  numpy first-occurrence argmin)
        unsigned long long u = (unsigned long long)__double_as_longlong(dist);
        u = (u >> 63) ? ~u : (u | 0x8000000000000000ULL);
        unsigned long long key = (u & ~7ULL) | (unsigned long long)kappa;
#pragma unroll
        for (int m = 1; m <= 4; m <<= 1) {
            unsigned long long ok = __shfl_xor(key, m, 64);
            key = (ok < key) ? ok : key;
        }
        const int widx = (int)(key & 7ULL);   // winner for token tau (group-wide)

        // cooperative z_q write: group grp owns token tau; round j writes the
        // contiguous 128B span chunks {8j..8j+7} (lane -> chunk gidx+8j).
        const long long row = tok0 + b * 8 + tau;
        float* qrow = zq + row * DIM;
        const float* erow = emb + widx * DIM;
#pragma unroll
        for (int j = 0; j < 8; ++j) {
            const int ch = gidx + 8 * j;
            const float4 q = *reinterpret_cast<const float4*>(erow + 4 * ch);
            *reinterpret_cast<float4*>(qrow + 4 * ch) = q;
        }
        if (gidx == 0) fidx[row] = (float)widx;
    }
}

extern "C" void kernel_launch(void* const* d_in, const int* in_sizes, int n_in,
                              void* d_out, int out_size, void* d_ws, size_t ws_size,
                              hipStream_t stream)
{
    const float* z   = (const float*)d_in[0];
    const float* emb = (const float*)d_in[1];
    float* out = (float*)d_out;

    const long long ntok = (long long)in_sizes[0] / DIM;   // 262144
    float* zq   = out;
    float* fidx = out + (size_t)ntok * DIM;

    const int blocks = (int)(ntok / (TPW * WPB));          // 2048

    vq_kernel<<<blocks, THREADS, 0, stream>>>(z, emb, zq, fidx);
}